// Round 11
// baseline (111.039 us; speedup 1.0000x reference)
//
#include <hip/hip_runtime.h>
#include <math.h>

#define BATCH 256
#define M 48
#define T 80
#define NF 6
#define EMIT 10
#define MM (M*M)        // 2304
#define NW 4            // waves per block (1 per SIMD: redundancy is free)
#define KPW 9           // keys per lane per wave (2304 / 64 / 4)
#define LOG2PI 1.8378770664093453f

typedef unsigned int u32;
typedef unsigned long long u64;

// Raw workgroup sync: drains LDS (lgkm) only -- async global_load_lds DMA
// (vmcnt) stays in flight. "memory" clobber stops compiler caching LDS in regs.
#define WGSYNC()     __asm__ __volatile__("s_waitcnt lgkmcnt(0)\ns_barrier" ::: "memory")
#define WGSYNC_ALL() __asm__ __volatile__("s_waitcnt vmcnt(0) lgkmcnt(0)\ns_barrier" ::: "memory")

// 4 waves/block (1/SIMD). Wave-parallel phases run REDUNDANTLY on all waves
// (free at 1 wave/SIMD). Deep work is SPLIT 4 ways with lgkm-only barriers.
// EM inner loop is register-resident: every wave holds all 48 P values in its
// lanes (redundant E-step); the M-step gathers P via in-wave shfl.
// NOTE: the shfl-gather M-step must be BRANCHLESS -- ds_bpermute reads from
// exec-masked-off lanes are undefined (R10 bug: `if (gid<18)` deactivated
// source lanes 16..63 in wave 2). All lanes compute; only writes are guarded.
__global__ __launch_bounds__(256, 1)
void em_kernel(const float* __restrict__ g_logits,
               const float* __restrict__ g_traj,
               const float* __restrict__ g_cov,
               float* __restrict__ g_out)
{
    const int b = blockIdx.x;
    const int tid = threadIdx.x;
    const int lane = tid & 63;
    const int wv = tid >> 6;
    const int SEL[3] = {29, 49, 79};

    // ---- LDS ~125 KB ----
    __shared__ __align__(16) float s_txy[M*T*2];    // staged traj (DMA)
    __shared__ __align__(16) float s_cv4[M*T*4];    // staged cov (DMA)
    __shared__ float s_adj[MM];
    __shared__ float s_logits[M];
    __shared__ float s_probas[M];
    __shared__ float s_tsel[M*6];                   // [m][tt][d]
    __shared__ float s_d1[M*3];
    __shared__ __align__(16) float s_csel[M*3*4];   // [m][tt]{c00,c01,c11,pad}
    __shared__ __align__(16) float s_Pm[M*8];       // written LAST iter only
    __shared__ __align__(16) float4 s_st[2][NF*3];  // {p00,p01,p11,ld} ping-pong
    __shared__ __align__(8)  float2 s_t6[2][NF*3];  // {tx,ty}
    __shared__ float s_probas6[2][NF];
    __shared__ int   s_idx[8];
    __shared__ __align__(16) u32 s_hist[NW][4][256]; // [wave][round] private
    __shared__ u32 s_statc[NW], s_statm[NW];

    const float* traj_b = g_traj + (size_t)b*(M*T*2);
    const float* cov_b  = g_cov  + (size_t)b*(M*T*4);

    // ========== direct gathers (redundant per wave) ==========
    float myLogit = -1e30f;
    if (lane < M) myLogit = g_logits[b*M + lane];
    float selx[3], sely[3], cc0[3], cc1[3], cc2[3];
    #pragma unroll
    for (int r = 0; r < 3; ++r) {
        int i = lane + r*64;
        if (i < M*3) {
            int m = i/3, tt = i - (i/3)*3;
            float2 xy = ((const float2*)traj_b)[m*T + SEL[tt]];
            float4 cv = ((const float4*)cov_b)[m*T + SEL[tt]];
            selx[r]=xy.x; sely[r]=xy.y; cc0[r]=cv.x; cc1[r]=cv.y; cc2[r]=cv.w;
        }
    }

    // ========== DMA staging, split 4 ways (per-wave vmcnt) ==========
    __builtin_amdgcn_sched_barrier(0);
    {
        const char* gt = (const char*)traj_b + lane*16;
        char* lt = (char*)s_txy;
        #pragma unroll 2
        for (int k = wv; k < 30; k += NW)
            __builtin_amdgcn_global_load_lds(
                (const __attribute__((address_space(1))) u32*)(gt + k*1024),
                (__attribute__((address_space(3))) u32*)(lt + k*1024), 16, 0, 0);
        const char* gc = (const char*)cov_b + lane*16;
        char* lc = (char*)s_cv4;
        #pragma unroll 2
        for (int k = wv; k < 60; k += NW)
            __builtin_amdgcn_global_load_lds(
                (const __attribute__((address_space(1))) u32*)(gc + k*1024),
                (__attribute__((address_space(3))) u32*)(lc + k*1024), 16, 0, 0);
    }
    __builtin_amdgcn_sched_barrier(0);

    // ========== zero own hist buffers (program-order before own atomics) ====
    {
        uint4* hz = (uint4*)&s_hist[wv][0][0];     // 4*256 u32 = 256 uint4
        #pragma unroll
        for (int k = 0; k < 4; ++k) hz[lane + k*64] = make_uint4(0,0,0,0);
    }

    // ========== stage selector data (redundant identical writes) ==========
    if (lane < M) s_logits[lane] = myLogit;
    #pragma unroll
    for (int r = 0; r < 3; ++r) {
        int i = lane + r*64;
        if (i < M*3) {
            int m = i/3, tt = i - (i/3)*3;
            s_tsel[m*6+tt*2+0] = selx[r];
            s_tsel[m*6+tt*2+1] = sely[r];
            s_d1[i] = selx[r]*selx[r] + sely[r]*sely[r];
            s_csel[i*4+0]=cc0[r]; s_csel[i*4+1]=cc1[r]; s_csel[i*4+2]=cc2[r]; s_csel[i*4+3]=0.f;
        }
    }

    // ========== softmax (in-wave, registers; redundant per wave) ==========
    float mx = myLogit;
    #pragma unroll
    for (int off = 32; off; off >>= 1) mx = fmaxf(mx, __shfl_xor(mx, off));
    float pe = (lane < M) ? __expf(myLogit - mx) : 0.f;
    float psum = pe;
    #pragma unroll
    for (int off = 32; off; off >>= 1) psum += __shfl_xor(psum, off);
    const float proba = pe / psum;
    if (lane < M) s_probas[lane] = proba;

    // ========== SQUARED distances all 3 tt (split: 9/lane) + round-1 hist ====
    u32 key[KPW];
    float sq0[KPW], sq1[KPW];
    {
        u32* h0 = &s_hist[wv][0][0];
        #pragma unroll
        for (int j = 0; j < KPW; ++j) {
            int e = lane + (wv*KPW + j)*64;
            int m = e/M, n = e - (e/M)*M;
            float dot2 = s_tsel[m*6+4]*s_tsel[n*6+4] + s_tsel[m*6+5]*s_tsel[n*6+5];
            float v2 = s_d1[m*3+2] + s_d1[n*3+2] - 2.0f*dot2;
            key[j] = __float_as_uint(fmaxf(v2, 0.0f));   // nonneg: uint order == float order
            float dot0 = s_tsel[m*6+0]*s_tsel[n*6+0] + s_tsel[m*6+1]*s_tsel[n*6+1];
            sq0[j] = fmaxf(s_d1[m*3+0] + s_d1[n*3+0] - 2.0f*dot0, 0.0f);
            float dot1 = s_tsel[m*6+2]*s_tsel[n*6+2] + s_tsel[m*6+3]*s_tsel[n*6+3];
            sq1[j] = fmaxf(s_d1[m*3+1] + s_d1[n*3+1] - 2.0f*dot1, 0.0f);
            atomicAdd(&h0[key[j] >> 24], 1u);
        }
    }

    // ========== exact order stat 345: 4-round radix over split keys ==========
    int target = 345;
    u32 prefix = 0u, pmask = 0u;
    #pragma unroll 1
    for (int r = 0; r < 4; ++r) {
        const int shift = 24 - 8*r;
        if (r) {
            u32* hr = &s_hist[wv][r][0];
            #pragma unroll
            for (int j = 0; j < KPW; ++j) {
                if ((key[j] & pmask) == prefix)
                    atomicAdd(&hr[(key[j] >> shift) & 255u], 1u);
            }
        }
        WGSYNC();   // own atomics drained; partners' partials visible
        u32 hx=0, hy=0, hz=0, hw=0;
        #pragma unroll
        for (int w = 0; w < NW; ++w) {
            uint4 h = ((const uint4*)&s_hist[w][r][0])[lane];
            hx += h.x; hy += h.y; hz += h.z; hw += h.w;
        }
        uint4 hv = make_uint4(hx, hy, hz, hw);
        u32 s4 = hv.x + hv.y + hv.z + hv.w;
        u32 cum = s4;
        #pragma unroll
        for (int off = 1; off < 64; off <<= 1) {
            u32 u = __shfl_up(cum, off);
            if (lane >= off) cum += u;
        }
        u64 bmask = __ballot(cum > (u32)target);
        int g = __builtin_ctzll(bmask);
        int dig = 0; u32 binstart = 0;
        if (lane == g) {
            u32 exc = cum - s4;
            int bi2 = lane*4;
            if (exc + hv.x > (u32)target)      { dig = bi2;   binstart = exc; }
            else { exc += hv.x;
                if (exc + hv.y > (u32)target)  { dig = bi2+1; binstart = exc; }
                else { exc += hv.y;
                    if (exc + hv.z > (u32)target) { dig = bi2+2; binstart = exc; }
                    else { exc += hv.z;            dig = bi2+3; binstart = exc; } } }
        }
        dig = __shfl(dig, g);
        binstart = (u32)__shfl((int)binstart, g);
        target -= (int)binstart;
        prefix |= ((u32)dig) << shift;
        pmask  |= (255u << shift);
    }
    const u32 k1 = prefix;                 // squared order stat 345
    const float v1f = sqrtf(__uint_as_float(k1));

    // ========== order stat 346: split partials + 1-barrier combine ==========
    {
        u32 cnt = 0, mng = 0xFFFFFFFFu;
        #pragma unroll
        for (int j = 0; j < KPW; ++j) {
            if (key[j] <= k1) cnt++;
            else mng = (key[j] < mng) ? key[j] : mng;
        }
        #pragma unroll
        for (int off = 32; off > 0; off >>= 1) {
            cnt += __shfl_down(cnt, off);
            u32 mo = (u32)__shfl_down((int)mng, off);
            mng = (mo < mng) ? mo : mng;
        }
        if (lane == 0) { s_statc[wv] = cnt; s_statm[wv] = mng; }
    }
    WGSYNC();
    float v2f;
    {
        u32 ct = 0, mt = 0xFFFFFFFFu;
        #pragma unroll
        for (int w = 0; w < NW; ++w) {
            ct += s_statc[w];
            if (s_statm[w] < mt) mt = s_statm[w];
        }
        v2f = (ct >= 347u) ? v1f : sqrtf(__uint_as_float(mt));
    }
    const float qi = 0.15f * 2303.0f;
    const float fr = qi - floorf(qi);
    const float thr = v1f*(1.0f - fr) + v2f*fr;

    // exact squared threshold: dthr = max{u : fl(sqrt(u)) <= thr}
    float dthr;
    {
        u32 ub = __float_as_uint(thr*thr);
        while (sqrtf(__uint_as_float(ub)) > thr) --ub;        // <=2 iters
        while (sqrtf(__uint_as_float(ub+1u)) <= thr) ++ub;    // <=2 iters
        dthr = __uint_as_float(ub);
    }

    // ========== adjacency: pure compare+store from cached registers ==========
    #pragma unroll
    for (int j = 0; j < KPW; ++j) {
        int e = lane + (wv*KPW + j)*64;
        bool a = (__uint_as_float(key[j]) <= dthr) && (sq0[j] <= dthr) && (sq1[j] <= dthr);
        s_adj[e] = a ? 1.0f : 0.0f;
    }
    WGSYNC();

    // ========== greedy selection (redundant per wave) ==========
    const int m = (lane < M) ? lane : (M-1);
    {
        float base = 0.f;
        #pragma unroll
        for (int n = 0; n < M; ++n) base += s_adj[n*M+m] * s_probas[n];
        float worked = 1.f;
        #pragma unroll 1
        for (int k = 0; k < NF; ++k) {
            float sc = (lane < M) ? base*worked : -1.f;
            int bi = lane;
            #pragma unroll
            for (int off = 32; off; off >>= 1) {
                float so = __shfl_down(sc, off);
                int io = __shfl_down(bi, off);
                if (so > sc || (so == sc && io < bi)) { sc = so; bi = io; }
            }
            int amax = __shfl(bi, 0);   // first-max == jnp.argmax
            if (lane == 0) s_idx[k] = amax;
            worked *= (1.f - s_adj[amax*M+m]);
        }
    }

    // ========== EM init -> buffer 0 (redundant identical writes) ==========
    if (lane < NF) {
        float mx6 = -1e30f;
        #pragma unroll
        for (int j = 0; j < NF; ++j) mx6 = fmaxf(mx6, s_logits[s_idx[j]]);
        float sum6 = 0.f;
        #pragma unroll
        for (int j = 0; j < NF; ++j) sum6 += __expf(s_logits[s_idx[j]] - mx6);
        s_probas6[0][lane] = __expf(s_logits[s_idx[lane]] - mx6) / sum6;
    }
    if (lane < NF*3) {
        int n = lane/3, tt = lane - (lane/3)*3;
        int m0 = s_idx[n];
        s_t6[0][lane] = make_float2(s_tsel[m0*6+tt*2+0], s_tsel[m0*6+tt*2+1]);
        float c00 = s_csel[(m0*3+tt)*4+0];
        float c01 = s_csel[(m0*3+tt)*4+1];
        float c11 = s_csel[(m0*3+tt)*4+2];
        float det = c00*c11 - c01*c01;
        float rdet = __fdividef(1.0f, det);
        s_st[0][lane] = make_float4(c11*rdet, -c01*rdet, c00*rdet, __logf(det));
    }

    // ========== EM loop: redundant E-step + branchless register M-step ======
    float tm0=s_tsel[m*6+0], tm1=s_tsel[m*6+1], tm2=s_tsel[m*6+2],
          tm3=s_tsel[m*6+3], tm4=s_tsel[m*6+4], tm5=s_tsel[m*6+5];
    const int gid = tid >> 3;          // 8-lane group id; writers: gid<18
    const int sub = tid & 7;
    const int gn  = gid/3, gtt = gid - (gid/3)*3;
    const int gnc = (gn < NF) ? gn : NF-1;             // clamp for dead lanes
    float*  out_p = g_out;

    // preload M-step features (ALL lanes; indices in range, dead lanes unused)
    float fx[6], fy[6], fc0[6], fc1[6], fc2[6];
    #pragma unroll
    for (int k = 0; k < 6; ++k) {
        int mm = sub*6 + k;
        fx[k] = s_tsel[mm*6+gtt*2+0];
        fy[k] = s_tsel[mm*6+gtt*2+1];
        float4 c4 = *(const float4*)&s_csel[(mm*3+gtt)*4];
        fc0[k]=c4.x; fc1[k]=c4.y; fc2[k]=c4.z;
    }

    #pragma unroll 1
    for (int it = 0; it < EMIT; ++it) {
        const int cur = it & 1, nxt = cur ^ 1;
        const float4* stC = s_st[cur];
        const float2* t6C = s_t6[cur];
        const float*  p6C = s_probas6[cur];

        // ---- E-step (all waves, lane = m): packed broadcast LDS reads ----
        float P[NF]; float den = 1e-8f;
        #pragma unroll
        for (int n = 0; n < NF; ++n) {
            float4 p0 = stC[n*3+0], p1 = stC[n*3+1], p2 = stC[n*3+2];
            float2 a0 = t6C[n*3+0], a1 = t6C[n*3+1], a2 = t6C[n*3+2];
            float lsum = p0.w + p1.w + p2.w;
            float dx0 = a0.x-tm0, dy0 = a0.y-tm1;
            float dx1 = a1.x-tm2, dy1 = a1.y-tm3;
            float dx2 = a2.x-tm4, dy2 = a2.y-tm5;
            float q = p0.x*dx0*dx0 + 2.f*p0.y*dx0*dy0 + p0.z*dy0*dy0
                    + p1.x*dx1*dx1 + 2.f*p1.y*dx1*dy1 + p1.z*dy1*dy1
                    + p2.x*dx2*dx2 + 2.f*p2.y*dx2*dy2 + p2.z*dy2*dy2;
            P[n] = (__expf(-3.f*LOG2PI - 0.5f*lsum - 0.5f*q) + 1e-8f) * p6C[n];
            den += P[n];
        }
        float f = __fdividef(proba, den);
        #pragma unroll
        for (int n = 0; n < NF; ++n) P[n] *= f;   // 0 for lanes >= M (proba==0)

        if (it == EMIT-1) {
            if (lane < M) {   // publish P for the final full-T M-step
                *(float4*)&s_Pm[m*8]   = make_float4(P[0], P[1], P[2], 0.f);
                *(float4*)&s_Pm[m*8+4] = make_float4(P[3], P[4], P[5], 0.f);
            }
            // probas6 output from wave 3's registers (wv uniform: whole wave active)
            if (wv == 3) {
                #pragma unroll
                for (int n = 0; n < NF; ++n) {
                    float v = P[n];
                    #pragma unroll
                    for (int off = 32; off; off >>= 1) v += __shfl_down(v, off);
                    if (lane == 0) out_p[b*NF + n] = v;
                }
            }
            break;
        }

        // ---- selector M-step: BRANCHLESS shfl gather (all lanes active so
        //      bpermute source lanes 0..47 are defined); writes guarded ----
        {
            float SP=0,S1x=0,S1y=0,Sxx=0,Sxy=0,Syy=0,C0=0,C1=0,C2=0;
            #pragma unroll
            for (int k = 0; k < 6; ++k) {
                int src = sub*6 + k;
                float q0 = __shfl(P[0], src), q1 = __shfl(P[1], src), q2 = __shfl(P[2], src);
                float q3 = __shfl(P[3], src), q4 = __shfl(P[4], src), q5 = __shfl(P[5], src);
                float p = (gnc==0)?q0:(gnc==1)?q1:(gnc==2)?q2:(gnc==3)?q3:(gnc==4)?q4:q5;
                SP += p; S1x += p*fx[k]; S1y += p*fy[k];
                Sxx += p*fx[k]*fx[k]; Sxy += p*fx[k]*fy[k]; Syy += p*fy[k]*fy[k];
                C0 += p*fc0[k]; C1 += p*fc1[k]; C2 += p*fc2[k];
            }
            #define R8_(v) { v += __shfl_down(v,4); v += __shfl_down(v,2); v += __shfl_down(v,1); }
            R8_(SP) R8_(S1x) R8_(S1y) R8_(Sxx) R8_(Sxy) R8_(Syy) R8_(C0) R8_(C1) R8_(C2)
            #undef R8_
            if (sub == 0 && gid < 18) {
                float p6 = SP;
                float tx = __fdividef(S1x, p6), ty = __fdividef(S1y, p6);
                float rp = __fdividef(1.0f, p6);
                float c00 = (C0 + (Sxx - S1x*tx)) * rp;
                float c01 = (C1 + (Sxy - S1x*ty)) * rp;
                float c11 = (C2 + (Syy - S1y*ty)) * rp;
                float det = c00*c11 - c01*c01;
                float rdet = __fdividef(1.0f, det);
                s_st[nxt][gid] = make_float4(c11*rdet, -c01*rdet, c00*rdet, __logf(det));
                s_t6[nxt][gid] = make_float2(tx, ty);
                if (gtt == 0) s_probas6[nxt][gn] = SP;
            }
        }
        WGSYNC();   // lgkm-only + s_barrier: DMA (vmcnt) stays in flight
    }

    // ========== full sync: DMA chunks + last E-step Pm visible ==========
    WGSYNC_ALL();

    // ========== final full-T M-step: 240 items=(t,third), 60 lanes/wave =======
    float2* out_t = (float2*)(g_out + BATCH*NF);
    float4* out_c = (float4*)(g_out + BATCH*NF + BATCH*NF*T*2);
    if (lane < 60) {
        int idx = wv*60 + lane;       // 0..239
        int t = idx/3, third = idx - (idx/3)*3;
        int nA = third*2, nB = nA + 1;
        int slotA = (nA < 3) ? nA : nA + 1;
        int slotB = (nB < 3) ? nB : nB + 1;
        float SPa=0,S1xa=0,S1ya=0,Sxxa=0,Sxya=0,Syya=0,C00a=0,C01a=0,C11a=0;
        float SPb=0,S1xb=0,S1yb=0,Sxxb=0,Sxyb=0,Syyb=0,C00b=0,C01b=0,C11b=0;
        #pragma unroll 4
        for (int mm = 0; mm < M; ++mm) {
            float2 xy = ((const float2*)s_txy)[mm*T + t];
            float4 c4 = ((const float4*)s_cv4)[mm*T + t];
            float pa = s_Pm[mm*8 + slotA];
            float pb = s_Pm[mm*8 + slotB];
            float xx = xy.x*xy.x, xyv = xy.x*xy.y, yy = xy.y*xy.y;
            SPa+=pa; S1xa+=pa*xy.x; S1ya+=pa*xy.y;
            Sxxa+=pa*xx; Sxya+=pa*xyv; Syya+=pa*yy;
            C00a+=pa*c4.x; C01a+=pa*c4.y; C11a+=pa*c4.w;
            SPb+=pb; S1xb+=pb*xy.x; S1yb+=pb*xy.y;
            Sxxb+=pb*xx; Sxyb+=pb*xyv; Syyb+=pb*yy;
            C00b+=pb*c4.x; C01b+=pb*c4.y; C11b+=pb*c4.w;
        }
        {
            float p6 = SPa;
            float tx = __fdividef(S1xa, p6), ty = __fdividef(S1ya, p6);
            float rp = __fdividef(1.0f, p6);
            float c00 = (C00a + (Sxxa - S1xa*tx)) * rp;
            float c01 = (C01a + (Sxya - S1xa*ty)) * rp;
            float c11 = (C11a + (Syya - S1ya*ty)) * rp;
            size_t o = (size_t)(b*NF + nA)*T + t;
            out_t[o] = make_float2(tx, ty);
            out_c[o] = make_float4(c00, c01, c01, c11);
        }
        {
            float p6 = SPb;
            float tx = __fdividef(S1xb, p6), ty = __fdividef(S1yb, p6);
            float rp = __fdividef(1.0f, p6);
            float c00 = (C00b + (Sxxb - S1xb*tx)) * rp;
            float c01 = (C01b + (Sxyb - S1xb*ty)) * rp;
            float c11 = (C11b + (Syyb - S1yb*ty)) * rp;
            size_t o = (size_t)(b*NF + nB)*T + t;
            out_t[o] = make_float2(tx, ty);
            out_c[o] = make_float4(c00, c01, c01, c11);
        }
    }
}

extern "C" void kernel_launch(void* const* d_in, const int* in_sizes, int n_in,
                              void* d_out, int out_size, void* d_ws, size_t ws_size,
                              hipStream_t stream) {
    const float* logits = (const float*)d_in[0];
    const float* traj   = (const float*)d_in[1];
    const float* cov    = (const float*)d_in[2];
    float* out = (float*)d_out;
    em_kernel<<<dim3(BATCH), dim3(256), 0, stream>>>(logits, traj, cov, out);
}

// Round 12
// 105.494 us; speedup vs baseline: 1.0526x; 1.0526x over previous
//
#include <hip/hip_runtime.h>
#include <math.h>

#define BATCH 256
#define M 48
#define T 80
#define NF 6
#define EMIT 10
#define MM (M*M)        // 2304
#define NW 4            // waves per block (1 per SIMD: redundancy is free)
#define KPW 9           // keys per lane per wave (2304 / 64 / 4)
#define LOG2PI 1.8378770664093453f

typedef unsigned int u32;
typedef unsigned long long u64;

// Raw workgroup sync: drains LDS (lgkm) only -- async global_load_lds DMA
// (vmcnt) stays in flight. "memory" clobber stops compiler caching LDS in regs.
#define WGSYNC()     __asm__ __volatile__("s_waitcnt lgkmcnt(0)\ns_barrier" ::: "memory")
#define WGSYNC_ALL() __asm__ __volatile__("s_waitcnt vmcnt(0) lgkmcnt(0)\ns_barrier" ::: "memory")

// 4 waves/block (1/SIMD). Wave-parallel phases (E-step, softmax, greedy) run
// REDUNDANTLY on all waves -- free at 1 wave/SIMD (R8: 2 waves/SIMD doubles
// their issue time). Deep work (DMA, keys, radix histograms, stat346,
// adjacency, selector M-step, final M-step) is SPLIT 4 ways with lgkm-only
// barriers. EM state ping-pongs, packed float4/float2.
// R11 lesson: __shfl is ds_bpermute (LDS pipe) -- replacing 6 ds_reads with
// 36 bpermutes regressed. This is the measured-optimal R9 configuration.
__global__ __launch_bounds__(256, 1)
void em_kernel(const float* __restrict__ g_logits,
               const float* __restrict__ g_traj,
               const float* __restrict__ g_cov,
               float* __restrict__ g_out)
{
    const int b = blockIdx.x;
    const int tid = threadIdx.x;
    const int lane = tid & 63;
    const int wv = tid >> 6;
    const int SEL[3] = {29, 49, 79};

    // ---- LDS ~125 KB ----
    __shared__ __align__(16) float s_txy[M*T*2];    // staged traj (DMA)
    __shared__ __align__(16) float s_cv4[M*T*4];    // staged cov (DMA)
    __shared__ float s_adj[MM];
    __shared__ float s_logits[M];
    __shared__ float s_probas[M];
    __shared__ float s_tsel[M*6];                   // [m][tt][d]
    __shared__ float s_d1[M*3];
    __shared__ __align__(16) float s_csel[M*3*4];   // [m][tt]{c00,c01,c11,pad}
    __shared__ __align__(16) float s_Pm[M*8];       // slots: 0-2=n0..2, 4-6=n3..5
    __shared__ __align__(16) float4 s_st[2][NF*3];  // {p00,p01,p11,ld} ping-pong
    __shared__ __align__(8)  float2 s_t6[2][NF*3];  // {tx,ty}
    __shared__ float s_probas6[2][NF];
    __shared__ int   s_idx[8];
    __shared__ __align__(16) u32 s_hist[NW][4][256]; // [wave][round] private
    __shared__ u32 s_statc[NW], s_statm[NW];

    const float* traj_b = g_traj + (size_t)b*(M*T*2);
    const float* cov_b  = g_cov  + (size_t)b*(M*T*4);

    // ========== direct gathers (redundant per wave) ==========
    float myLogit = -1e30f;
    if (lane < M) myLogit = g_logits[b*M + lane];
    float selx[3], sely[3], cc0[3], cc1[3], cc2[3];
    #pragma unroll
    for (int r = 0; r < 3; ++r) {
        int i = lane + r*64;
        if (i < M*3) {
            int m = i/3, tt = i - (i/3)*3;
            float2 xy = ((const float2*)traj_b)[m*T + SEL[tt]];
            float4 cv = ((const float4*)cov_b)[m*T + SEL[tt]];
            selx[r]=xy.x; sely[r]=xy.y; cc0[r]=cv.x; cc1[r]=cv.y; cc2[r]=cv.w;
        }
    }

    // ========== DMA staging, split 4 ways (per-wave vmcnt) ==========
    __builtin_amdgcn_sched_barrier(0);
    {
        const char* gt = (const char*)traj_b + lane*16;
        char* lt = (char*)s_txy;
        #pragma unroll 2
        for (int k = wv; k < 30; k += NW)
            __builtin_amdgcn_global_load_lds(
                (const __attribute__((address_space(1))) u32*)(gt + k*1024),
                (__attribute__((address_space(3))) u32*)(lt + k*1024), 16, 0, 0);
        const char* gc = (const char*)cov_b + lane*16;
        char* lc = (char*)s_cv4;
        #pragma unroll 2
        for (int k = wv; k < 60; k += NW)
            __builtin_amdgcn_global_load_lds(
                (const __attribute__((address_space(1))) u32*)(gc + k*1024),
                (__attribute__((address_space(3))) u32*)(lc + k*1024), 16, 0, 0);
    }
    __builtin_amdgcn_sched_barrier(0);

    // ========== zero own hist buffers (program-order before own atomics) ====
    {
        uint4* hz = (uint4*)&s_hist[wv][0][0];     // 4*256 u32 = 256 uint4
        #pragma unroll
        for (int k = 0; k < 4; ++k) hz[lane + k*64] = make_uint4(0,0,0,0);
    }

    // ========== stage selector data (redundant identical writes) ==========
    if (lane < M) s_logits[lane] = myLogit;
    #pragma unroll
    for (int r = 0; r < 3; ++r) {
        int i = lane + r*64;
        if (i < M*3) {
            int m = i/3, tt = i - (i/3)*3;
            s_tsel[m*6+tt*2+0] = selx[r];
            s_tsel[m*6+tt*2+1] = sely[r];
            s_d1[i] = selx[r]*selx[r] + sely[r]*sely[r];
            s_csel[i*4+0]=cc0[r]; s_csel[i*4+1]=cc1[r]; s_csel[i*4+2]=cc2[r]; s_csel[i*4+3]=0.f;
        }
    }

    // ========== softmax (in-wave, registers; redundant per wave) ==========
    float mx = myLogit;
    #pragma unroll
    for (int off = 32; off; off >>= 1) mx = fmaxf(mx, __shfl_xor(mx, off));
    float pe = (lane < M) ? __expf(myLogit - mx) : 0.f;
    float psum = pe;
    #pragma unroll
    for (int off = 32; off; off >>= 1) psum += __shfl_xor(psum, off);
    const float proba = pe / psum;
    if (lane < M) s_probas[lane] = proba;

    // ========== SQUARED distances all 3 tt (split: 9/lane) + round-1 hist ====
    u32 key[KPW];
    float sq0[KPW], sq1[KPW];
    {
        u32* h0 = &s_hist[wv][0][0];
        #pragma unroll
        for (int j = 0; j < KPW; ++j) {
            int e = lane + (wv*KPW + j)*64;
            int m = e/M, n = e - (e/M)*M;
            float dot2 = s_tsel[m*6+4]*s_tsel[n*6+4] + s_tsel[m*6+5]*s_tsel[n*6+5];
            float v2 = s_d1[m*3+2] + s_d1[n*3+2] - 2.0f*dot2;
            key[j] = __float_as_uint(fmaxf(v2, 0.0f));   // nonneg: uint order == float order
            float dot0 = s_tsel[m*6+0]*s_tsel[n*6+0] + s_tsel[m*6+1]*s_tsel[n*6+1];
            sq0[j] = fmaxf(s_d1[m*3+0] + s_d1[n*3+0] - 2.0f*dot0, 0.0f);
            float dot1 = s_tsel[m*6+2]*s_tsel[n*6+2] + s_tsel[m*6+3]*s_tsel[n*6+3];
            sq1[j] = fmaxf(s_d1[m*3+1] + s_d1[n*3+1] - 2.0f*dot1, 0.0f);
            atomicAdd(&h0[key[j] >> 24], 1u);
        }
    }

    // ========== exact order stat 345: 4-round radix over split keys ==========
    int target = 345;
    u32 prefix = 0u, pmask = 0u;
    #pragma unroll 1
    for (int r = 0; r < 4; ++r) {
        const int shift = 24 - 8*r;
        if (r) {
            u32* hr = &s_hist[wv][r][0];
            #pragma unroll
            for (int j = 0; j < KPW; ++j) {
                if ((key[j] & pmask) == prefix)
                    atomicAdd(&hr[(key[j] >> shift) & 255u], 1u);
            }
        }
        WGSYNC();   // own atomics drained; partners' partials visible
        u32 hx=0, hy=0, hz=0, hw=0;
        #pragma unroll
        for (int w = 0; w < NW; ++w) {
            uint4 h = ((const uint4*)&s_hist[w][r][0])[lane];
            hx += h.x; hy += h.y; hz += h.z; hw += h.w;
        }
        uint4 hv = make_uint4(hx, hy, hz, hw);
        u32 s4 = hv.x + hv.y + hv.z + hv.w;
        u32 cum = s4;
        #pragma unroll
        for (int off = 1; off < 64; off <<= 1) {
            u32 u = __shfl_up(cum, off);
            if (lane >= off) cum += u;
        }
        u64 bmask = __ballot(cum > (u32)target);
        int g = __builtin_ctzll(bmask);
        int dig = 0; u32 binstart = 0;
        if (lane == g) {
            u32 exc = cum - s4;
            int bi2 = lane*4;
            if (exc + hv.x > (u32)target)      { dig = bi2;   binstart = exc; }
            else { exc += hv.x;
                if (exc + hv.y > (u32)target)  { dig = bi2+1; binstart = exc; }
                else { exc += hv.y;
                    if (exc + hv.z > (u32)target) { dig = bi2+2; binstart = exc; }
                    else { exc += hv.z;            dig = bi2+3; binstart = exc; } } }
        }
        dig = __shfl(dig, g);
        binstart = (u32)__shfl((int)binstart, g);
        target -= (int)binstart;
        prefix |= ((u32)dig) << shift;
        pmask  |= (255u << shift);
    }
    const u32 k1 = prefix;                 // squared order stat 345
    const float v1f = sqrtf(__uint_as_float(k1));

    // ========== order stat 346: split partials + 1-barrier combine ==========
    {
        u32 cnt = 0, mng = 0xFFFFFFFFu;
        #pragma unroll
        for (int j = 0; j < KPW; ++j) {
            if (key[j] <= k1) cnt++;
            else mng = (key[j] < mng) ? key[j] : mng;
        }
        #pragma unroll
        for (int off = 32; off > 0; off >>= 1) {
            cnt += __shfl_down(cnt, off);
            u32 mo = (u32)__shfl_down((int)mng, off);
            mng = (mo < mng) ? mo : mng;
        }
        if (lane == 0) { s_statc[wv] = cnt; s_statm[wv] = mng; }
    }
    WGSYNC();
    float v2f;
    {
        u32 ct = 0, mt = 0xFFFFFFFFu;
        #pragma unroll
        for (int w = 0; w < NW; ++w) {
            ct += s_statc[w];
            if (s_statm[w] < mt) mt = s_statm[w];
        }
        v2f = (ct >= 347u) ? v1f : sqrtf(__uint_as_float(mt));
    }
    const float qi = 0.15f * 2303.0f;
    const float fr = qi - floorf(qi);
    const float thr = v1f*(1.0f - fr) + v2f*fr;

    // exact squared threshold: dthr = max{u : fl(sqrt(u)) <= thr}
    float dthr;
    {
        u32 ub = __float_as_uint(thr*thr);
        while (sqrtf(__uint_as_float(ub)) > thr) --ub;        // <=2 iters
        while (sqrtf(__uint_as_float(ub+1u)) <= thr) ++ub;    // <=2 iters
        dthr = __uint_as_float(ub);
    }

    // ========== adjacency: pure compare+store from cached registers ==========
    #pragma unroll
    for (int j = 0; j < KPW; ++j) {
        int e = lane + (wv*KPW + j)*64;
        bool a = (__uint_as_float(key[j]) <= dthr) && (sq0[j] <= dthr) && (sq1[j] <= dthr);
        s_adj[e] = a ? 1.0f : 0.0f;
    }
    WGSYNC();

    // ========== greedy selection (redundant per wave) ==========
    const int m = (lane < M) ? lane : (M-1);
    {
        float base = 0.f;
        #pragma unroll
        for (int n = 0; n < M; ++n) base += s_adj[n*M+m] * s_probas[n];
        float worked = 1.f;
        #pragma unroll 1
        for (int k = 0; k < NF; ++k) {
            float sc = (lane < M) ? base*worked : -1.f;
            int bi = lane;
            #pragma unroll
            for (int off = 32; off; off >>= 1) {
                float so = __shfl_down(sc, off);
                int io = __shfl_down(bi, off);
                if (so > sc || (so == sc && io < bi)) { sc = so; bi = io; }
            }
            int amax = __shfl(bi, 0);   // first-max == jnp.argmax
            if (lane == 0) s_idx[k] = amax;
            worked *= (1.f - s_adj[amax*M+m]);
        }
    }

    // ========== EM init -> buffer 0 (redundant identical writes) ==========
    if (lane < NF) {
        float mx6 = -1e30f;
        #pragma unroll
        for (int j = 0; j < NF; ++j) mx6 = fmaxf(mx6, s_logits[s_idx[j]]);
        float sum6 = 0.f;
        #pragma unroll
        for (int j = 0; j < NF; ++j) sum6 += __expf(s_logits[s_idx[j]] - mx6);
        s_probas6[0][lane] = __expf(s_logits[s_idx[lane]] - mx6) / sum6;
    }
    if (lane < NF*3) {
        int n = lane/3, tt = lane - (lane/3)*3;
        int m0 = s_idx[n];
        s_t6[0][lane] = make_float2(s_tsel[m0*6+tt*2+0], s_tsel[m0*6+tt*2+1]);
        float c00 = s_csel[(m0*3+tt)*4+0];
        float c01 = s_csel[(m0*3+tt)*4+1];
        float c11 = s_csel[(m0*3+tt)*4+2];
        float det = c00*c11 - c01*c01;
        float rdet = __fdividef(1.0f, det);
        s_st[0][lane] = make_float4(c11*rdet, -c01*rdet, c00*rdet, __logf(det));
    }

    // ========== EM loop: redundant E-step + SPLIT selector M-step ==========
    float tm0=s_tsel[m*6+0], tm1=s_tsel[m*6+1], tm2=s_tsel[m*6+2],
          tm3=s_tsel[m*6+3], tm4=s_tsel[m*6+4], tm5=s_tsel[m*6+5];
    const int gid = tid >> 3;          // 8-lane group id; 18 active (waves 0-2)
    const int sub = tid & 7;
    const int gn  = gid/3, gtt = gid - (gid/3)*3;      // valid when gid<18
    const int gslot = (gn < 3) ? gn : gn + 1;
    float*  out_p = g_out;

    #pragma unroll 1
    for (int it = 0; it < EMIT; ++it) {
        const int cur = it & 1, nxt = cur ^ 1;
        const float4* stC = s_st[cur];
        const float2* t6C = s_t6[cur];
        const float*  p6C = s_probas6[cur];

        // ---- E-step (all waves, lane = m): packed broadcast LDS reads ----
        float num[NF]; float den = 1e-8f;
        #pragma unroll
        for (int n = 0; n < NF; ++n) {
            float4 p0 = stC[n*3+0], p1 = stC[n*3+1], p2 = stC[n*3+2];
            float2 a0 = t6C[n*3+0], a1 = t6C[n*3+1], a2 = t6C[n*3+2];
            float lsum = p0.w + p1.w + p2.w;
            float dx0 = a0.x-tm0, dy0 = a0.y-tm1;
            float dx1 = a1.x-tm2, dy1 = a1.y-tm3;
            float dx2 = a2.x-tm4, dy2 = a2.y-tm5;
            float q = p0.x*dx0*dx0 + 2.f*p0.y*dx0*dy0 + p0.z*dy0*dy0
                    + p1.x*dx1*dx1 + 2.f*p1.y*dx1*dy1 + p1.z*dy1*dy1
                    + p2.x*dx2*dx2 + 2.f*p2.y*dx2*dy2 + p2.z*dy2*dy2;
            num[n] = (__expf(-3.f*LOG2PI - 0.5f*lsum - 0.5f*q) + 1e-8f) * p6C[n];
            den += num[n];
        }
        float f = __fdividef(proba, den);
        if (lane < M) {   // identical-value writes from all waves: race-safe
            *(float4*)&s_Pm[m*8]   = make_float4(num[0]*f, num[1]*f, num[2]*f, 0.f);
            *(float4*)&s_Pm[m*8+4] = make_float4(num[3]*f, num[4]*f, num[5]*f, 0.f);
        }
        if (it == EMIT-1) {
            // probas6 output from wave 3's registers (no staging dependency);
            // overlaps the other waves' path to the final barrier.
            if (wv == 3) {
                #pragma unroll
                for (int n = 0; n < NF; ++n) {
                    float v = num[n]*f;      // 0 for lanes >= M (proba==0)
                    #pragma unroll
                    for (int off = 32; off; off >>= 1) v += __shfl_down(v, off);
                    if (lane == 0) out_p[b*NF + n] = v;
                }
            }
            break;
        }

        // ---- selector M-step SPLIT: 18 items x 8-lane groups, 6-deep loops ----
        if (gid < 18) {
            float SP=0,S1x=0,S1y=0,Sxx=0,Sxy=0,Syy=0,C0=0,C1=0,C2=0;
            #pragma unroll
            for (int k = 0; k < 6; ++k) {
                int mm = sub*6 + k;
                float p = s_Pm[mm*8 + gslot];     // own-wave writes: in-order visible
                float x = s_tsel[mm*6+gtt*2+0];
                float y = s_tsel[mm*6+gtt*2+1];
                float4 c4 = *(const float4*)&s_csel[(mm*3+gtt)*4];
                SP += p; S1x += p*x; S1y += p*y;
                Sxx += p*x*x; Sxy += p*x*y; Syy += p*y*y;
                C0 += p*c4.x; C1 += p*c4.y; C2 += p*c4.z;
            }
            #define R8_(v) { v += __shfl_down(v,4); v += __shfl_down(v,2); v += __shfl_down(v,1); }
            R8_(SP) R8_(S1x) R8_(S1y) R8_(Sxx) R8_(Sxy) R8_(Syy) R8_(C0) R8_(C1) R8_(C2)
            #undef R8_
            if (sub == 0) {
                float p6 = SP;
                float tx = __fdividef(S1x, p6), ty = __fdividef(S1y, p6);
                float rp = __fdividef(1.0f, p6);
                float c00 = (C0 + (Sxx - S1x*tx)) * rp;
                float c01 = (C1 + (Sxy - S1x*ty)) * rp;
                float c11 = (C2 + (Syy - S1y*ty)) * rp;
                float det = c00*c11 - c01*c01;
                float rdet = __fdividef(1.0f, det);
                s_st[nxt][gid] = make_float4(c11*rdet, -c01*rdet, c00*rdet, __logf(det));
                s_t6[nxt][gid] = make_float2(tx, ty);
                if (gtt == 0) s_probas6[nxt][gn] = SP;
            }
        }
        WGSYNC();   // lgkm-only + s_barrier: DMA (vmcnt) stays in flight
    }

    // ========== full sync: DMA chunks + last E-step visible ==========
    WGSYNC_ALL();

    // ========== final full-T M-step: 240 items=(t,third), 60 lanes/wave =======
    float2* out_t = (float2*)(g_out + BATCH*NF);
    float4* out_c = (float4*)(g_out + BATCH*NF + BATCH*NF*T*2);
    if (lane < 60) {
        int idx = wv*60 + lane;       // 0..239
        int t = idx/3, third = idx - (idx/3)*3;
        int nA = third*2, nB = nA + 1;
        int slotA = (nA < 3) ? nA : nA + 1;
        int slotB = (nB < 3) ? nB : nB + 1;
        float SPa=0,S1xa=0,S1ya=0,Sxxa=0,Sxya=0,Syya=0,C00a=0,C01a=0,C11a=0;
        float SPb=0,S1xb=0,S1yb=0,Sxxb=0,Sxyb=0,Syyb=0,C00b=0,C01b=0,C11b=0;
        #pragma unroll 4
        for (int mm = 0; mm < M; ++mm) {
            float2 xy = ((const float2*)s_txy)[mm*T + t];
            float4 c4 = ((const float4*)s_cv4)[mm*T + t];
            float pa = s_Pm[mm*8 + slotA];
            float pb = s_Pm[mm*8 + slotB];
            float xx = xy.x*xy.x, xyv = xy.x*xy.y, yy = xy.y*xy.y;
            SPa+=pa; S1xa+=pa*xy.x; S1ya+=pa*xy.y;
            Sxxa+=pa*xx; Sxya+=pa*xyv; Syya+=pa*yy;
            C00a+=pa*c4.x; C01a+=pa*c4.y; C11a+=pa*c4.w;
            SPb+=pb; S1xb+=pb*xy.x; S1yb+=pb*xy.y;
            Sxxb+=pb*xx; Sxyb+=pb*xyv; Syyb+=pb*yy;
            C00b+=pb*c4.x; C01b+=pb*c4.y; C11b+=pb*c4.w;
        }
        {
            float p6 = SPa;
            float tx = __fdividef(S1xa, p6), ty = __fdividef(S1ya, p6);
            float rp = __fdividef(1.0f, p6);
            float c00 = (C00a + (Sxxa - S1xa*tx)) * rp;
            float c01 = (C01a + (Sxya - S1xa*ty)) * rp;
            float c11 = (C11a + (Syya - S1ya*ty)) * rp;
            size_t o = (size_t)(b*NF + nA)*T + t;
            out_t[o] = make_float2(tx, ty);
            out_c[o] = make_float4(c00, c01, c01, c11);
        }
        {
            float p6 = SPb;
            float tx = __fdividef(S1xb, p6), ty = __fdividef(S1yb, p6);
            float rp = __fdividef(1.0f, p6);
            float c00 = (C00b + (Sxxb - S1xb*tx)) * rp;
            float c01 = (C01b + (Sxyb - S1xb*ty)) * rp;
            float c11 = (C11b + (Syyb - S1yb*ty)) * rp;
            size_t o = (size_t)(b*NF + nB)*T + t;
            out_t[o] = make_float2(tx, ty);
            out_c[o] = make_float4(c00, c01, c01, c11);
        }
    }
}

extern "C" void kernel_launch(void* const* d_in, const int* in_sizes, int n_in,
                              void* d_out, int out_size, void* d_ws, size_t ws_size,
                              hipStream_t stream) {
    const float* logits = (const float*)d_in[0];
    const float* traj   = (const float*)d_in[1];
    const float* cov    = (const float*)d_in[2];
    float* out = (float*)d_out;
    em_kernel<<<dim3(BATCH), dim3(256), 0, stream>>>(logits, traj, cov, out);
}